// Round 11
// baseline (1768.888 us; speedup 1.0000x reference)
//
#include <hip/hip_runtime.h>
#include <hip/hip_bf16.h>

#define T_ 2048
#define B_ 1024
#define H_ 256
#define I_ 8
#define A_ 8
#define DT_ 0.1f
#define EPS_ 1e-5f
#define LSTR 304  // bf16/row: 152 dwords -> row starts banks {0,24,16,8}
#define CH 32     // x-staging chunk (timesteps)
#define RB 4      // real batch rows per block (4-way aliased in 16-slot MFMA tiles)

typedef __attribute__((ext_vector_type(8))) short bf16x8;
typedef __attribute__((ext_vector_type(4))) float f32x4;

#if __has_builtin(__builtin_amdgcn_cvt_pk_bf16_f32)
typedef __attribute__((ext_vector_type(2))) __bf16 bf16x2;
__device__ __forceinline__ int pk2bf(float a, float b) {
    bf16x2 r = __builtin_amdgcn_cvt_pk_bf16_f32(a, b);
    return __builtin_bit_cast(int, r);
}
#else
__device__ __forceinline__ short f2bf1(float f) {
    unsigned u = __builtin_bit_cast(unsigned, f);
    u += 0x7fffu + ((u >> 16) & 1u);   // RNE
    return (short)(u >> 16);
}
__device__ __forceinline__ int pk2bf(float a, float b) {
    return (int)(unsigned short)f2bf1(a) | ((int)f2bf1(b) << 16);
}
#endif

// xor-16 / xor-32 butterfly sums on the VALU (off the LDS pipe) [R8-verified]
__device__ __forceinline__ float foldswap16(float x) {
    float a = x, b = x;
    asm("v_permlane16_swap_b32 %0, %1" : "+v"(a), "+v"(b));
    return a + b;
}
__device__ __forceinline__ float foldswap32(float x) {
    float a = x, b = x;
    asm("v_permlane32_swap_b32 %0, %1" : "+v"(a), "+v"(b));
    return a + b;
}

// lgkm-only barrier: skip __syncthreads()'s vmcnt(0) drain so x-prefetch
// global loads stay in flight across step barriers. [R8-verified]
__device__ __forceinline__ void bar_lgkm() {
    asm volatile("s_waitcnt lgkmcnt(0)\n\ts_barrier" ::: "memory");
}

__launch_bounds__(512, 2)
__global__ void liquid_kernel(const float* __restrict__ x,
                              const float* __restrict__ W_in,
                              const float* __restrict__ b_in,
                              const float* __restrict__ tau_param,
                              const float* __restrict__ W_rec,
                              const float* __restrict__ g1,
                              const float* __restrict__ beta1,
                              const float* __restrict__ g2,
                              const float* __restrict__ beta2,
                              const float* __restrict__ head_w,
                              const float* __restrict__ head_b,
                              float* __restrict__ out) {
    __shared__ short  h_lds[RB * LSTR];          // h_t (bf16), 4 real rows
    __shared__ short  xstage[2][CH][RB][8];      // x chunks (bf16)
    __shared__ alignas(16) float2 redt[RB][10];  // LN partials [row][wave(8)+pad]
    __shared__ float  hw[H_ * A_];               // head_w staging
    __shared__ float  outp[8][RB][A_];           // epilogue head partials

    const int tid  = threadIdx.x;
    const int w    = tid >> 6;    // wave 0..7 -> owns s-cols [w*32, w*32+32)
    const int lane = tid & 63;
    const int quad = lane >> 4;
    const int l15  = lane & 15;
    const int row  = l15 & 3;     // batch-row (4 aliased copies: l15, +4, +8, +12)
    const int cj   = l15 >> 2;    // copy index 0..3 -> tail subset
    const int mtj  = cj >> 1;     // which mt tile this lane's tail handles
    const int rbs  = (cj & 1) * 2; // which r-pair
    const int r0   = blockIdx.x * RB;

    for (int i = tid; i < RB * LSTR; i += 512) h_lds[i] = 0;

    // ---- per-lane params ----
    f32x4 pbin0, pbin1;                      // C-seeds for mt0/mt1 (column-based)
    float p_g1s[2], p_b1s[2], p_decay[2];    // for the 2 owned tail cols
#pragma unroll
    for (int r = 0; r < 4; ++r) {
        pbin0[r] = b_in[w * 32 + quad * 4 + r];
        pbin1[r] = b_in[w * 32 + 16 + quad * 4 + r];
    }
#pragma unroll
    for (int s = 0; s < 2; ++s) {
        int c = w * 32 + mtj * 16 + quad * 4 + rbs + s;
        p_g1s[s] = g1[c] * 2.885390082f;     // fold tanh's 2/ln2 scale
        p_b1s[s] = beta1[c] * 2.885390082f;
        float tp = tau_param[c];
        float sp = (tp > 20.f) ? tp : log1pf(expf(tp));  // softplus
        p_decay[s] = 1.0f - DT_ / sp;
    }

    // ---- A fragments resident in regs: A[m=l15][k=quad*8+j] = W_ext[k][cA] ----
    // W_ext rows 0..255 = W_rec, 256..263 = W_in, 264..287 = 0
    bf16x8 afrag[2][9];
#pragma unroll
    for (int mt = 0; mt < 2; ++mt) {
        int cA = w * 32 + mt * 16 + l15;
#pragma unroll
        for (int ks = 0; ks < 9; ++ks) {
            bf16x8 f;
#pragma unroll
            for (int j = 0; j < 8; ++j) {
                int kg = ks * 32 + quad * 8 + j;
                float v;
                if (kg < 256)      v = W_rec[kg * H_ + cA];
                else if (kg < 264) v = W_in[(kg - 256) * H_ + cA];
                else               v = 0.f;
                f[j] = (short)pk2bf(v, v);
            }
            afrag[mt][ks] = f;
        }
    }

    // ---- x chunk loader: threads 0..255, one float4/chunk each ----
    const int xrow = (tid >> 6) & 3, xf4 = tid & 63;     // row 0..3, f4 idx 0..63
    const int xt = xf4 >> 1, xi0 = (xf4 & 1) * 4;
    const bool xldr = (tid < 256);
    const float* xrbase = x + (size_t)(r0 + xrow) * T_ * I_;
    float4 xr;

    if (xldr) {
        xr = ((const float4*)xrbase)[xf4];               // chunk 0
        int2 pk = make_int2(pk2bf(xr.x, xr.y), pk2bf(xr.z, xr.w));
        *reinterpret_cast<int2*>(&xstage[0][xt][xrow][xi0]) = pk;
        xr = ((const float4*)(xrbase + (size_t)CH * I_))[xf4];  // chunk 1
    }

    float hreg[2];
    hreg[0] = 0.f; hreg[1] = 0.f;

    const short* hrow = &h_lds[row * LSTR + quad * 8];
    const f32x4 zacc = {0.f, 0.f, 0.f, 0.f};
    const bf16x8 zb = {0, 0, 0, 0, 0, 0, 0, 0};

    __syncthreads();   // h zeros + chunk0 visible (full sync once, pre-loop)

    // prefetch x B-frag for t=0 (quads 1-3 carry zeros in regs)
    bf16x8 xbr = zb;
    if (quad == 0) xbr = *reinterpret_cast<const bf16x8*>(&xstage[0][0][row][0]);

    for (int t = 0; t < T_; ++t) {
        const int tc  = t & (CH - 1);
        const int c   = t >> 5;
        const int buf = c & 1;

        bar_lgkm();       // barrier #1: h_t visible

        if (xldr && tc == 16) {   // convert held regs (chunk c+1) into idle buffer
            int2 pk = make_int2(pk2bf(xr.x, xr.y), pk2bf(xr.z, xr.w));
            *reinterpret_cast<int2*>(&xstage[buf ^ 1][xt][xrow][xi0]) = pk;
        }
        if (xldr && tc == 18) {   // issue loads for chunk c+2
            int cc = c + 2; if (cc > (T_ / CH) - 1) cc = (T_ / CH) - 1;
            xr = ((const float4*)(xrbase + (size_t)cc * CH * I_))[xf4];
        }

        // ---- GEMM: 6 chains (2 mt x 3 k-thirds), dep depth 3 ----
        // chain a: x + ks0 + ks1 ; chain b: ks2..4 ; chain c: ks5..7
        f32x4 c0a = pbin0, c1a = pbin1;
        f32x4 c0b = zacc, c1b = zacc, c0c = zacc, c1c = zacc;
        c0a = __builtin_amdgcn_mfma_f32_16x16x32_bf16(afrag[0][8], xbr, c0a, 0, 0, 0);
        c1a = __builtin_amdgcn_mfma_f32_16x16x32_bf16(afrag[1][8], xbr, c1a, 0, 0, 0);
        {
            bf16x8 b0 = *reinterpret_cast<const bf16x8*>(hrow + 0 * 32);
            bf16x8 b1 = *reinterpret_cast<const bf16x8*>(hrow + 1 * 32);
            bf16x8 b2 = *reinterpret_cast<const bf16x8*>(hrow + 2 * 32);
            bf16x8 b3 = *reinterpret_cast<const bf16x8*>(hrow + 3 * 32);
            bf16x8 b4 = *reinterpret_cast<const bf16x8*>(hrow + 4 * 32);
            bf16x8 b5 = *reinterpret_cast<const bf16x8*>(hrow + 5 * 32);
            bf16x8 b6 = *reinterpret_cast<const bf16x8*>(hrow + 6 * 32);
            bf16x8 b7 = *reinterpret_cast<const bf16x8*>(hrow + 7 * 32);
            c0a = __builtin_amdgcn_mfma_f32_16x16x32_bf16(afrag[0][0], b0, c0a, 0, 0, 0);
            c1a = __builtin_amdgcn_mfma_f32_16x16x32_bf16(afrag[1][0], b0, c1a, 0, 0, 0);
            c0b = __builtin_amdgcn_mfma_f32_16x16x32_bf16(afrag[0][2], b2, c0b, 0, 0, 0);
            c1b = __builtin_amdgcn_mfma_f32_16x16x32_bf16(afrag[1][2], b2, c1b, 0, 0, 0);
            c0c = __builtin_amdgcn_mfma_f32_16x16x32_bf16(afrag[0][5], b5, c0c, 0, 0, 0);
            c1c = __builtin_amdgcn_mfma_f32_16x16x32_bf16(afrag[1][5], b5, c1c, 0, 0, 0);
            c0a = __builtin_amdgcn_mfma_f32_16x16x32_bf16(afrag[0][1], b1, c0a, 0, 0, 0);
            c1a = __builtin_amdgcn_mfma_f32_16x16x32_bf16(afrag[1][1], b1, c1a, 0, 0, 0);
            c0b = __builtin_amdgcn_mfma_f32_16x16x32_bf16(afrag[0][3], b3, c0b, 0, 0, 0);
            c1b = __builtin_amdgcn_mfma_f32_16x16x32_bf16(afrag[1][3], b3, c1b, 0, 0, 0);
            c0c = __builtin_amdgcn_mfma_f32_16x16x32_bf16(afrag[0][6], b6, c0c, 0, 0, 0);
            c1c = __builtin_amdgcn_mfma_f32_16x16x32_bf16(afrag[1][6], b6, c1c, 0, 0, 0);
            c0b = __builtin_amdgcn_mfma_f32_16x16x32_bf16(afrag[0][4], b4, c0b, 0, 0, 0);
            c1b = __builtin_amdgcn_mfma_f32_16x16x32_bf16(afrag[1][4], b4, c1b, 0, 0, 0);
            c0c = __builtin_amdgcn_mfma_f32_16x16x32_bf16(afrag[0][7], b7, c0c, 0, 0, 0);
            c1c = __builtin_amdgcn_mfma_f32_16x16x32_bf16(afrag[1][7], b7, c1c, 0, 0, 0);
        }
        f32x4 acc0 = (c0a + c0b) + c0c, acc1 = (c1a + c1b) + c1c;

        // ---- LN partial: in-lane fold (quad's 8 cols) + 2 permlane hops ----
        float S  = ((acc0[0] + acc0[1]) + (acc0[2] + acc0[3]))
                 + ((acc1[0] + acc1[1]) + (acc1[2] + acc1[3]));
        float SQ = fmaf(acc0[0], acc0[0], fmaf(acc0[1], acc0[1],
                   fmaf(acc0[2], acc0[2], acc0[3] * acc0[3])))
                 + fmaf(acc1[0], acc1[0], fmaf(acc1[1], acc1[1],
                   fmaf(acc1[2], acc1[2], acc1[3] * acc1[3])));
        S = foldswap16(S);  SQ = foldswap16(SQ);
        S = foldswap32(S);  SQ = foldswap32(SQ);
        if (lane < RB) redt[row][w] = make_float2(S, SQ);  // quad0, copy0 only

        bar_lgkm();       // barrier #2: all wave partials in redt

        // ---- final stats: 4x ds_read_b128 (8 wave partials), broadcast rows ----
        const float4* rrow = reinterpret_cast<const float4*>(&redt[row][0]);
        float4 q0 = rrow[0], q1 = rrow[1], q2 = rrow[2], q3 = rrow[3];
        float St  = ((q0.x + q0.z) + (q1.x + q1.z)) + ((q2.x + q2.z) + (q3.x + q3.z));
        float SQt = ((q0.y + q0.w) + (q1.y + q1.w)) + ((q2.y + q2.w) + (q3.y + q3.w));
        const float mu   = St * (1.f / 256.f);
        const float var  = fmaf(SQt, 1.f / 256.f, -mu * mu);
        const float rstd = __builtin_amdgcn_rsqf(var + EPS_);
        const float nmr  = -mu * rstd;

        // ---- tail: this lane's 2 assigned values (mt=mtj, r=rbs..rbs+1) ----
        f32x4 vsrc = mtj ? acc1 : acc0;
#pragma unroll
        for (int s = 0; s < 2; ++s) {
            float v  = vsrc[rbs + s];
            float tt = fmaf(v, rstd, nmr);
            float z2 = fmaf(tt, p_g1s[s], p_b1s[s]);            // 2z/ln2
            float e  = __builtin_amdgcn_exp2f(z2);              // e^(2z)
            float rc = __builtin_amdgcn_rcpf(e + 1.f);
            float fd = fmaf(rc, -2.f * DT_, DT_);               // DT*tanh(z)
            float h  = fmaf(hreg[s], p_decay[s], fd);
            hreg[s]  = __builtin_amdgcn_fmed3f(h, -10.f, 10.f);
        }
        // pack: one ds_write_b32 per lane (2 bf16)
        *reinterpret_cast<int*>(&h_lds[row * LSTR + w * 32 + mtj * 16 + quad * 4 + rbs])
            = pk2bf(hreg[0], hreg[1]);

        // ---- prefetch x B-frag for step t+1 (xstage data stable >=15 steps;
        // conversion writes target buf^1, we read buf(t+1) -- disjoint) ----
        {
            const int tn  = (t + 1 < T_) ? t + 1 : t;
            const int tcn = tn & (CH - 1), bufn = (tn >> 5) & 1;
            xbr = zb;
            if (quad == 0)
                xbr = *reinterpret_cast<const bf16x8*>(&xstage[bufn][tcn][row][0]);
        }
    }

    // ---- epilogue: out = LN(h_T; g2,b2) @ head_w + head_b ----
    for (int i = tid; i < H_ * A_; i += 512) hw[i] = head_w[i];
    __syncthreads();

    float S2  = hreg[0] + hreg[1];
    float SQ2 = fmaf(hreg[0], hreg[0], hreg[1] * hreg[1]);
    S2 += __shfl_xor(S2, 4, 64);   SQ2 += __shfl_xor(SQ2, 4, 64);
    S2 += __shfl_xor(S2, 8, 64);   SQ2 += __shfl_xor(SQ2, 8, 64);
    S2 += __shfl_xor(S2, 16, 64);  SQ2 += __shfl_xor(SQ2, 16, 64);
    S2 += __shfl_xor(S2, 32, 64);  SQ2 += __shfl_xor(SQ2, 32, 64);
    if (lane < RB) redt[row][w] = make_float2(S2, SQ2);
    __syncthreads();
    const float4* rrow = reinterpret_cast<const float4*>(&redt[row][0]);
    float4 q0 = rrow[0], q1 = rrow[1], q2 = rrow[2], q3 = rrow[3];
    float St  = ((q0.x + q0.z) + (q1.x + q1.z)) + ((q2.x + q2.z) + (q3.x + q3.z));
    float SQt = ((q0.y + q0.w) + (q1.y + q1.w)) + ((q2.y + q2.w) + (q3.y + q3.w));
    const float mu   = St * (1.f / 256.f);
    const float var  = fmaf(SQt, 1.f / 256.f, -mu * mu);
    const float rstd = __builtin_amdgcn_rsqf(var + EPS_);

    float pa[8];
#pragma unroll
    for (int a = 0; a < 8; ++a) pa[a] = 0.f;
#pragma unroll
    for (int s = 0; s < 2; ++s) {
        int cc = w * 32 + mtj * 16 + quad * 4 + rbs + s;
        float lnh = (hreg[s] - mu) * rstd * g2[cc] + beta2[cc];
        float4 w0 = *reinterpret_cast<const float4*>(&hw[cc * 8]);
        float4 w1 = *reinterpret_cast<const float4*>(&hw[cc * 8 + 4]);
        pa[0] += lnh * w0.x; pa[1] += lnh * w0.y; pa[2] += lnh * w0.z; pa[3] += lnh * w0.w;
        pa[4] += lnh * w1.x; pa[5] += lnh * w1.y; pa[6] += lnh * w1.z; pa[7] += lnh * w1.w;
    }
#pragma unroll
    for (int a = 0; a < 8; ++a) {
        pa[a] += __shfl_xor(pa[a], 4, 64);
        pa[a] += __shfl_xor(pa[a], 8, 64);
        pa[a] += __shfl_xor(pa[a], 16, 64);
        pa[a] += __shfl_xor(pa[a], 32, 64);
    }
    if (lane < RB) {
#pragma unroll
        for (int a = 0; a < 8; ++a) outp[w][row][a] = pa[a];
    }
    __syncthreads();
    if (tid < RB * A_) {
        int r = tid >> 3, a = tid & 7;
        float s = head_b[a];
#pragma unroll
        for (int ww = 0; ww < 8; ++ww) s += outp[ww][r][a];
        out[(size_t)(r0 + r) * A_ + a] = s;
    }
}

extern "C" void kernel_launch(void* const* d_in, const int* in_sizes, int n_in,
                              void* d_out, int out_size, void* d_ws, size_t ws_size,
                              hipStream_t stream) {
    const float* x         = (const float*)d_in[0];
    const float* W_in      = (const float*)d_in[1];
    const float* b_in      = (const float*)d_in[2];
    const float* tau_param = (const float*)d_in[3];
    const float* W_rec     = (const float*)d_in[4];
    const float* g1        = (const float*)d_in[5];
    const float* beta1     = (const float*)d_in[6];
    const float* g2        = (const float*)d_in[7];
    const float* beta2     = (const float*)d_in[8];
    const float* head_w    = (const float*)d_in[9];
    const float* head_b    = (const float*)d_in[10];
    float* out = (float*)d_out;

    liquid_kernel<<<256, 512, 0, stream>>>(x, W_in, b_in, tau_param, W_rec,
                                           g1, beta1, g2, beta2, head_w, head_b, out);
}

// Round 14
// 1718.292 us; speedup vs baseline: 1.0294x; 1.0294x over previous
//
#include <hip/hip_runtime.h>
#include <hip/hip_bf16.h>

#define T_ 2048
#define B_ 1024
#define H_ 256
#define I_ 8
#define A_ 8
#define DT_ 0.1f
#define EPS_ 1e-5f
#define LSTR 304  // bf16/row: 152 dwords -> row starts banks {0,24,16,8}
#define CH 32     // x-staging chunk (timesteps)
#define RB 4      // real batch rows per block (4-way aliased in 16-slot MFMA tiles)

typedef __attribute__((ext_vector_type(8))) short bf16x8;
typedef __attribute__((ext_vector_type(4))) float f32x4;

#if __has_builtin(__builtin_amdgcn_cvt_pk_bf16_f32)
typedef __attribute__((ext_vector_type(2))) __bf16 bf16x2;
__device__ __forceinline__ int pk2bf(float a, float b) {
    bf16x2 r = __builtin_amdgcn_cvt_pk_bf16_f32(a, b);
    return __builtin_bit_cast(int, r);
}
#else
__device__ __forceinline__ short f2bf1(float f) {
    unsigned u = __builtin_bit_cast(unsigned, f);
    u += 0x7fffu + ((u >> 16) & 1u);   // RNE
    return (short)(u >> 16);
}
__device__ __forceinline__ int pk2bf(float a, float b) {
    return (int)(unsigned short)f2bf1(a) | ((int)f2bf1(b) << 16);
}
#endif

// xor-16 butterfly sum via VALU permlane (replaces ds_bpermute shfl): with
// a=b=x, permlane16_swap gives a'={r0,r0,r2,r2}, b'={r1,r1,r3,r3} -> a'+b' =
// x + x^16 in every lane. Same math as __shfl_xor(x,16), off the LDS pipe.
__device__ __forceinline__ float foldswap16(float x) {
    float a = x, b = x;
    asm("v_permlane16_swap_b32 %0, %1" : "+v"(a), "+v"(b));
    return a + b;
}
__device__ __forceinline__ float foldswap32(float x) {
    float a = x, b = x;
    asm("v_permlane32_swap_b32 %0, %1" : "+v"(a), "+v"(b));
    return a + b;
}

// Barrier with lgkm-only drain: __syncthreads() emits s_waitcnt vmcnt(0)
// lgkmcnt(0) which drains the in-flight x-prefetch global loads every step.
// Only LDS (lgkm) ordering is needed for h/partial visibility.
__device__ __forceinline__ void bar_lgkm() {
    asm volatile("s_waitcnt lgkmcnt(0)\n\ts_barrier" ::: "memory");
}

__launch_bounds__(512, 2)
__global__ void liquid_kernel(const float* __restrict__ x,
                              const float* __restrict__ W_in,
                              const float* __restrict__ b_in,
                              const float* __restrict__ tau_param,
                              const float* __restrict__ W_rec,
                              const float* __restrict__ g1,
                              const float* __restrict__ beta1,
                              const float* __restrict__ g2,
                              const float* __restrict__ beta2,
                              const float* __restrict__ head_w,
                              const float* __restrict__ head_b,
                              float* __restrict__ out) {
    __shared__ short  h_lds[RB * LSTR];          // h_t (bf16), 4 real rows
    __shared__ short  xstage[2][CH][RB][8];      // x chunks (bf16)
    __shared__ alignas(16) float2 redt[RB][10];  // LN partials [row][wave(8)+pad]
    __shared__ float  hw[H_ * A_];               // head_w staging
    __shared__ float  outp[8][RB][A_];           // epilogue head partials

    const int tid  = threadIdx.x;
    const int w    = tid >> 6;    // wave 0..7 -> owns s-cols [w*32, w*32+32)
    const int lane = tid & 63;
    const int quad = lane >> 4;
    const int l15  = lane & 15;
    const int row  = l15 & 3;     // batch-row (4 aliased copies: l15, +4, +8, +12)
    const int cj   = l15 >> 2;    // copy index 0..3 -> tail subset
    const int mtj  = cj >> 1;     // which mt tile this lane's tail handles
    const int rbs  = (cj & 1) * 2; // which r-pair
    const int r0   = blockIdx.x * RB;

    for (int i = tid; i < RB * LSTR; i += 512) h_lds[i] = 0;

    // ---- per-lane params ----
    f32x4 pbin0, pbin1;                      // C-seeds for mt0/mt1 (column-based)
    float p_g1s[2], p_b1s[2], p_decay[2];    // for the 2 owned tail cols
#pragma unroll
    for (int r = 0; r < 4; ++r) {
        pbin0[r] = b_in[w * 32 + quad * 4 + r];
        pbin1[r] = b_in[w * 32 + 16 + quad * 4 + r];
    }
#pragma unroll
    for (int s = 0; s < 2; ++s) {
        int c = w * 32 + mtj * 16 + quad * 4 + rbs + s;
        p_g1s[s] = g1[c] * 2.885390082f;     // fold tanh's 2/ln2 scale
        p_b1s[s] = beta1[c] * 2.885390082f;
        float tp = tau_param[c];
        float sp = (tp > 20.f) ? tp : log1pf(expf(tp));  // softplus
        p_decay[s] = 1.0f - DT_ / sp;
    }

    // ---- A fragments resident in regs: A[m=l15][k=quad*8+j] = W_ext[k][cA] ----
    // W_ext rows 0..255 = W_rec, 256..263 = W_in, 264..287 = 0
    bf16x8 afrag[2][9];
#pragma unroll
    for (int mt = 0; mt < 2; ++mt) {
        int cA = w * 32 + mt * 16 + l15;
#pragma unroll
        for (int ks = 0; ks < 9; ++ks) {
            bf16x8 f;
#pragma unroll
            for (int j = 0; j < 8; ++j) {
                int kg = ks * 32 + quad * 8 + j;
                float v;
                if (kg < 256)      v = W_rec[kg * H_ + cA];
                else if (kg < 264) v = W_in[(kg - 256) * H_ + cA];
                else               v = 0.f;
                f[j] = (short)pk2bf(v, v);
            }
            afrag[mt][ks] = f;
        }
    }

    // ---- x chunk loader: threads 0..255, one float4/chunk each ----
    const int xrow = (tid >> 6) & 3, xf4 = tid & 63;     // row 0..3, f4 idx 0..63
    const int xt = xf4 >> 1, xi0 = (xf4 & 1) * 4;
    const bool xldr = (tid < 256);
    const float* xrbase = x + (size_t)(r0 + xrow) * T_ * I_;
    float4 xr;

    if (xldr) {
        xr = ((const float4*)xrbase)[xf4];               // chunk 0
        int2 pk = make_int2(pk2bf(xr.x, xr.y), pk2bf(xr.z, xr.w));
        *reinterpret_cast<int2*>(&xstage[0][xt][xrow][xi0]) = pk;
        xr = ((const float4*)(xrbase + (size_t)CH * I_))[xf4];  // chunk 1
    }

    float hreg[2];
    hreg[0] = 0.f; hreg[1] = 0.f;

    const short* hrow = &h_lds[row * LSTR + quad * 8];
    const f32x4 zacc = {0.f, 0.f, 0.f, 0.f};
    const bf16x8 zb = {0, 0, 0, 0, 0, 0, 0, 0};

    __syncthreads();   // h zeros + chunk0 visible (full sync once, pre-loop)

    // prefetch x B-frag for t=0 (quads 1-3 carry zeros in regs)
    bf16x8 xbr = zb;
    if (quad == 0) xbr = *reinterpret_cast<const bf16x8*>(&xstage[0][0][row][0]);

    for (int t = 0; t < T_; ++t) {
        const int tc  = t & (CH - 1);
        const int c   = t >> 5;
        const int buf = c & 1;

        bar_lgkm();       // barrier #1: h_t visible

        if (xldr && tc == 16) {   // convert held regs (chunk c+1) into idle buffer
            int2 pk = make_int2(pk2bf(xr.x, xr.y), pk2bf(xr.z, xr.w));
            *reinterpret_cast<int2*>(&xstage[buf ^ 1][xt][xrow][xi0]) = pk;
        }
        if (xldr && tc == 18) {   // issue loads for chunk c+2
            int cc = c + 2; if (cc > (T_ / CH) - 1) cc = (T_ / CH) - 1;
            xr = ((const float4*)(xrbase + (size_t)cc * CH * I_))[xf4];
        }

        // ---- GEMM: 4 chains (2 mt x 2 k-halves); x-MFMA issues first (xbr is
        // already in regs, no dependence on the post-barrier h-read burst) ----
        f32x4 c0a = pbin0, c1a = pbin1, c0b = zacc, c1b = zacc;
        c0a = __builtin_amdgcn_mfma_f32_16x16x32_bf16(afrag[0][8], xbr, c0a, 0, 0, 0);
        c1a = __builtin_amdgcn_mfma_f32_16x16x32_bf16(afrag[1][8], xbr, c1a, 0, 0, 0);
#pragma unroll
        for (int ks = 0; ks < 4; ++ks) {
            bf16x8 bA = *reinterpret_cast<const bf16x8*>(hrow + ks * 32);
            bf16x8 bB = *reinterpret_cast<const bf16x8*>(hrow + (ks + 4) * 32);
            c0a = __builtin_amdgcn_mfma_f32_16x16x32_bf16(afrag[0][ks],     bA, c0a, 0, 0, 0);
            c1a = __builtin_amdgcn_mfma_f32_16x16x32_bf16(afrag[1][ks],     bA, c1a, 0, 0, 0);
            c0b = __builtin_amdgcn_mfma_f32_16x16x32_bf16(afrag[0][ks + 4], bB, c0b, 0, 0, 0);
            c1b = __builtin_amdgcn_mfma_f32_16x16x32_bf16(afrag[1][ks + 4], bB, c1b, 0, 0, 0);
        }
        f32x4 acc0 = c0a + c0b, acc1 = c1a + c1b;

        // ---- LN partial: in-lane fold (quad's 8 cols) + 2 permlane hops ----
        float S  = ((acc0[0] + acc0[1]) + (acc0[2] + acc0[3]))
                 + ((acc1[0] + acc1[1]) + (acc1[2] + acc1[3]));
        float SQ = fmaf(acc0[0], acc0[0], fmaf(acc0[1], acc0[1],
                   fmaf(acc0[2], acc0[2], acc0[3] * acc0[3])))
                 + fmaf(acc1[0], acc1[0], fmaf(acc1[1], acc1[1],
                   fmaf(acc1[2], acc1[2], acc1[3] * acc1[3])));
        S = foldswap16(S);  SQ = foldswap16(SQ);
        S = foldswap32(S);  SQ = foldswap32(SQ);
        if (lane < RB) redt[row][w] = make_float2(S, SQ);  // quad0, copy0 only

        bar_lgkm();       // barrier #2: all wave partials in redt

        // ---- final stats: 4x ds_read_b128 (8 wave partials), broadcast rows ----
        const float4* rrow = reinterpret_cast<const float4*>(&redt[row][0]);
        float4 q0 = rrow[0], q1 = rrow[1], q2 = rrow[2], q3 = rrow[3];
        float St  = ((q0.x + q0.z) + (q1.x + q1.z)) + ((q2.x + q2.z) + (q3.x + q3.z));
        float SQt = ((q0.y + q0.w) + (q1.y + q1.w)) + ((q2.y + q2.w) + (q3.y + q3.w));
        const float mu   = St * (1.f / 256.f);
        const float var  = fmaf(SQt, 1.f / 256.f, -mu * mu);
        const float rstd = __builtin_amdgcn_rsqf(var + EPS_);
        const float nmr  = -mu * rstd;

        // ---- tail: this lane's 2 assigned values (mt=mtj, r=rbs..rbs+1) ----
        f32x4 vsrc = mtj ? acc1 : acc0;
#pragma unroll
        for (int s = 0; s < 2; ++s) {
            float v  = vsrc[rbs + s];
            float tt = fmaf(v, rstd, nmr);
            float z2 = fmaf(tt, p_g1s[s], p_b1s[s]);            // 2z/ln2
            float e  = __builtin_amdgcn_exp2f(z2);              // e^(2z)
            float rc = __builtin_amdgcn_rcpf(e + 1.f);
            float fd = fmaf(rc, -2.f * DT_, DT_);               // DT*tanh(z)
            float h  = fmaf(hreg[s], p_decay[s], fd);
            hreg[s]  = __builtin_amdgcn_fmed3f(h, -10.f, 10.f);
        }
        // pack: one ds_write_b32 per lane (2 bf16)
        *reinterpret_cast<int*>(&h_lds[row * LSTR + w * 32 + mtj * 16 + quad * 4 + rbs])
            = pk2bf(hreg[0], hreg[1]);

        // ---- prefetch x B-frag for step t+1 (xstage data stable >=15 steps;
        // conversion writes target buf^1, we read buf(t+1) -- disjoint) ----
        {
            const int tn  = (t + 1 < T_) ? t + 1 : t;
            const int tcn = tn & (CH - 1), bufn = (tn >> 5) & 1;
            xbr = zb;
            if (quad == 0)
                xbr = *reinterpret_cast<const bf16x8*>(&xstage[bufn][tcn][row][0]);
        }
    }

    // ---- epilogue: out = LN(h_T; g2,b2) @ head_w + head_b ----
    for (int i = tid; i < H_ * A_; i += 512) hw[i] = head_w[i];
    __syncthreads();

    float S2  = hreg[0] + hreg[1];
    float SQ2 = fmaf(hreg[0], hreg[0], hreg[1] * hreg[1]);
    S2 += __shfl_xor(S2, 4, 64);   SQ2 += __shfl_xor(SQ2, 4, 64);
    S2 += __shfl_xor(S2, 8, 64);   SQ2 += __shfl_xor(SQ2, 8, 64);
    S2 += __shfl_xor(S2, 16, 64);  SQ2 += __shfl_xor(SQ2, 16, 64);
    S2 += __shfl_xor(S2, 32, 64);  SQ2 += __shfl_xor(SQ2, 32, 64);
    if (lane < RB) redt[row][w] = make_float2(S2, SQ2);
    __syncthreads();
    const float4* rrow = reinterpret_cast<const float4*>(&redt[row][0]);
    float4 q0 = rrow[0], q1 = rrow[1], q2 = rrow[2], q3 = rrow[3];
    float St  = ((q0.x + q0.z) + (q1.x + q1.z)) + ((q2.x + q2.z) + (q3.x + q3.z));
    float SQt = ((q0.y + q0.w) + (q1.y + q1.w)) + ((q2.y + q2.w) + (q3.y + q3.w));
    const float mu   = St * (1.f / 256.f);
    const float var  = fmaf(SQt, 1.f / 256.f, -mu * mu);
    const float rstd = __builtin_amdgcn_rsqf(var + EPS_);

    float pa[8];
#pragma unroll
    for (int a = 0; a < 8; ++a) pa[a] = 0.f;
#pragma unroll
    for (int s = 0; s < 2; ++s) {
        int cc = w * 32 + mtj * 16 + quad * 4 + rbs + s;
        float lnh = (hreg[s] - mu) * rstd * g2[cc] + beta2[cc];
        float4 w0 = *reinterpret_cast<const float4*>(&hw[cc * 8]);
        float4 w1 = *reinterpret_cast<const float4*>(&hw[cc * 8 + 4]);
        pa[0] += lnh * w0.x; pa[1] += lnh * w0.y; pa[2] += lnh * w0.z; pa[3] += lnh * w0.w;
        pa[4] += lnh * w1.x; pa[5] += lnh * w1.y; pa[6] += lnh * w1.z; pa[7] += lnh * w1.w;
    }
#pragma unroll
    for (int a = 0; a < 8; ++a) {
        pa[a] += __shfl_xor(pa[a], 4, 64);
        pa[a] += __shfl_xor(pa[a], 8, 64);
        pa[a] += __shfl_xor(pa[a], 16, 64);
        pa[a] += __shfl_xor(pa[a], 32, 64);
    }
    if (lane < RB) {
#pragma unroll
        for (int a = 0; a < 8; ++a) outp[w][row][a] = pa[a];
    }
    __syncthreads();
    if (tid < RB * A_) {
        int r = tid >> 3, a = tid & 7;
        float s = head_b[a];
#pragma unroll
        for (int ww = 0; ww < 8; ++ww) s += outp[ww][r][a];
        out[(size_t)(r0 + r) * A_ + a] = s;
    }
}

extern "C" void kernel_launch(void* const* d_in, const int* in_sizes, int n_in,
                              void* d_out, int out_size, void* d_ws, size_t ws_size,
                              hipStream_t stream) {
    const float* x         = (const float*)d_in[0];
    const float* W_in      = (const float*)d_in[1];
    const float* b_in      = (const float*)d_in[2];
    const float* tau_param = (const float*)d_in[3];
    const float* W_rec     = (const float*)d_in[4];
    const float* g1        = (const float*)d_in[5];
    const float* beta1     = (const float*)d_in[6];
    const float* g2        = (const float*)d_in[7];
    const float* beta2     = (const float*)d_in[8];
    const float* head_w    = (const float*)d_in[9];
    const float* head_b    = (const float*)d_in[10];
    float* out = (float*)d_out;

    liquid_kernel<<<256, 512, 0, stream>>>(x, W_in, b_in, tau_param, W_rec,
                                           g1, beta1, g2, beta2, head_w, head_b, out);
}